// Round 1
// baseline (2700.327 us; speedup 1.0000x reference)
//
#include <hip/hip_runtime.h>
#include <stddef.h>

#define HH 96
#define WW 96
#define NPIX 9216
#define LBL 21
#define LPAD 32
#define RAD 9            // int(3 * POS_STD)
#define N_ITER 10
#define POS_W_C 3.0f
#define POS_STD_C 3.0f
#define BI_W_C 10.0f
#define INV_XY (1.0f/80.0f)
#define INV_RGB (1.0f/13.0f)

typedef __bf16 bf16x8 __attribute__((ext_vector_type(8)));
typedef float  f32x4  __attribute__((ext_vector_type(4)));

__device__ __forceinline__ unsigned short f2bf(float f) {
    // round-to-nearest-even float32 -> bf16 (values here are finite)
    unsigned u = __float_as_uint(f);
    unsigned r = (u + 0x7fffu + ((u >> 16) & 1u)) >> 16;
    return (unsigned short)r;
}

// ---------------------------------------------------------------- k_prep
// features (SoA), spatial normalizer nsp = rsqrt(Sy[y]*Sx[x])
__global__ void k_prep(const float* __restrict__ I,
                       float* __restrict__ fx, float* __restrict__ fy,
                       float* __restrict__ fr, float* __restrict__ fg,
                       float* __restrict__ fb, float* __restrict__ nsp) {
    int n = blockIdx.x * 256 + threadIdx.x;
    if (n >= NPIX) return;
    int y = n / WW, x = n % WW;
    fx[n] = (float)x * INV_XY;
    fy[n] = (float)y * INV_XY;
    fr[n] = I[n] * INV_RGB;
    fg[n] = I[NPIX + n] * INV_RGB;
    fb[n] = I[2 * NPIX + n] * INV_RGB;
    float sy = 0.f, sx = 0.f;
    #pragma unroll
    for (int d = -RAD; d <= RAD; ++d) {
        float g = __expf(-0.5f * ((float)d / POS_STD_C) * ((float)d / POS_STD_C));
        if ((unsigned)(y + d) < HH) sy += g;
        if ((unsigned)(x + d) < WW) sx += g;
    }
    nsp[n] = rsqrtf(sy * sx);
}

// ---------------------------------------------------------------- k_K
// one block per row i: K[i][j] (bf16, optional) + nbi[i] = rsqrt(sum_j K)
template <bool STORE>
__global__ void k_K(const float* __restrict__ fx, const float* __restrict__ fy,
                    const float* __restrict__ fr, const float* __restrict__ fg,
                    const float* __restrict__ fb,
                    float* __restrict__ nbi, unsigned short* __restrict__ K) {
    int i = blockIdx.x;
    int t = threadIdx.x;
    float xi = fx[i], yi = fy[i], ri = fr[i], gi = fg[i], bi = fb[i];
    float sum = 0.f;
    for (int jt = t; jt < NPIX / 4; jt += 256) {
        int j = jt * 4;
        float4 vx = *(const float4*)(fx + j);
        float4 vy = *(const float4*)(fy + j);
        float4 vr = *(const float4*)(fr + j);
        float4 vg = *(const float4*)(fg + j);
        float4 vb = *(const float4*)(fb + j);
        float k0, k1, k2, k3;
        {
            float dx = xi - vx.x, dy = yi - vy.x, dr = ri - vr.x, dg = gi - vg.x, db = bi - vb.x;
            k0 = __expf(-0.5f * (dx*dx + dy*dy + dr*dr + dg*dg + db*db));
        }
        {
            float dx = xi - vx.y, dy = yi - vy.y, dr = ri - vr.y, dg = gi - vg.y, db = bi - vb.y;
            k1 = __expf(-0.5f * (dx*dx + dy*dy + dr*dr + dg*dg + db*db));
        }
        {
            float dx = xi - vx.z, dy = yi - vy.z, dr = ri - vr.z, dg = gi - vg.z, db = bi - vb.z;
            k2 = __expf(-0.5f * (dx*dx + dy*dy + dr*dr + dg*dg + db*db));
        }
        {
            float dx = xi - vx.w, dy = yi - vy.w, dr = ri - vr.w, dg = gi - vg.w, db = bi - vb.w;
            k3 = __expf(-0.5f * (dx*dx + dy*dy + dr*dr + dg*dg + db*db));
        }
        sum += (k0 + k1) + (k2 + k3);
        if (STORE) {
            ushort4 s;
            s.x = f2bf(k0); s.y = f2bf(k1); s.z = f2bf(k2); s.w = f2bf(k3);
            *(ushort4*)(K + (size_t)i * NPIX + j) = s;
        }
    }
    __shared__ float red[256];
    red[t] = sum;
    __syncthreads();
    #pragma unroll
    for (int s = 128; s > 0; s >>= 1) {
        if (t < s) red[t] += red[t + s];
        __syncthreads();
    }
    if (t == 0) nbi[i] = rsqrtf(red[0]);
}

// ---------------------------------------------------------------- k_q0
// Q0 = softmax(-U); Qt0 = bf16(nbi*Q0), label-major [32][NPIX]; zero pad rows
__global__ void k_q0(const float* __restrict__ U, const float* __restrict__ nbi,
                     float* __restrict__ Q,
                     unsigned short* __restrict__ Qt0, unsigned short* __restrict__ Qt1) {
    int n = blockIdx.x * 256 + threadIdx.x;
    if (n >= NPIX) return;
    float v[LBL];
    float mx = -1e30f;
    #pragma unroll
    for (int l = 0; l < LBL; ++l) { v[l] = -U[l * NPIX + n]; mx = fmaxf(mx, v[l]); }
    float s = 0.f;
    #pragma unroll
    for (int l = 0; l < LBL; ++l) { v[l] = __expf(v[l] - mx); s += v[l]; }
    float inv = 1.f / s;
    float nb = nbi[n];
    #pragma unroll
    for (int l = 0; l < LBL; ++l) {
        float q = v[l] * inv;
        Q[l * NPIX + n] = q;
        Qt0[l * NPIX + n] = f2bf(nb * q);
    }
    #pragma unroll
    for (int l = LBL; l < LPAD; ++l) { Qt0[l * NPIX + n] = 0; Qt1[l * NPIX + n] = 0; }
}

// ---------------------------------------------------------------- k_spatial
// SP[l] = POS_W * nsp * conv_sep19(nsp * Q[l]); one block per label
__global__ void k_spatial(const float* __restrict__ Q, const float* __restrict__ nsp,
                          float* __restrict__ SP) {
    __shared__ float a[NPIX];
    int l = blockIdx.x;
    int t = threadIdx.x;
    float g[2 * RAD + 1];
    #pragma unroll
    for (int d = 0; d <= 2 * RAD; ++d) {
        float z = (float)(d - RAD) / POS_STD_C;
        g[d] = __expf(-0.5f * z * z);
    }
    #pragma unroll
    for (int c = 0; c < NPIX / 256; ++c) {
        int n = t + c * 256;
        a[n] = nsp[n] * Q[l * NPIX + n];
    }
    __syncthreads();
    float vv[NPIX / 256];
    #pragma unroll
    for (int c = 0; c < NPIX / 256; ++c) {
        int n = t + c * 256;
        int y = n / WW, x = n % WW;
        float s = 0.f;
        #pragma unroll
        for (int d = -RAD; d <= RAD; ++d) {
            int yy = y + d;
            if ((unsigned)yy < HH) s += g[d + RAD] * a[yy * WW + x];
        }
        vv[c] = s;
    }
    __syncthreads();
    #pragma unroll
    for (int c = 0; c < NPIX / 256; ++c) a[t + c * 256] = vv[c];
    __syncthreads();
    #pragma unroll
    for (int c = 0; c < NPIX / 256; ++c) {
        int n = t + c * 256;
        int y = n / WW, x = n % WW;
        float s = 0.f;
        #pragma unroll
        for (int d = -RAD; d <= RAD; ++d) {
            int xx = x + d;
            if ((unsigned)xx < WW) s += g[d + RAD] * a[y * WW + xx];
        }
        SP[l * NPIX + n] = POS_W_C * nsp[n] * s;
    }
}

// ---------------------------------------------------------------- k_bi_fast
// one wave per 16 pixels; full-j MFMA GEMM over bf16 K; fused softmax epilogue
__global__ void __launch_bounds__(64)
k_bi_fast(const unsigned short* __restrict__ K, const unsigned short* __restrict__ Qt,
          const float* __restrict__ U, const float* __restrict__ SP,
          const float* __restrict__ nbi,
          float* __restrict__ Qo, unsigned short* __restrict__ Qto) {
    int lane = threadIdx.x;
    int m  = lane & 15;     // A row / B col / label index
    int kh = lane >> 4;     // k-quad
    int i0 = blockIdx.x * 16;

    const bf16x8* pa  = (const bf16x8*)(K  + (size_t)(i0 + m) * NPIX + kh * 8);
    const bf16x8* pb0 = (const bf16x8*)(Qt + (size_t)m        * NPIX + kh * 8);
    const bf16x8* pb1 = (const bf16x8*)(Qt + (size_t)(m + 16) * NPIX + kh * 8);

    f32x4 acc0 = {0.f, 0.f, 0.f, 0.f};
    f32x4 acc1 = {0.f, 0.f, 0.f, 0.f};

    #pragma unroll 4
    for (int jt = 0; jt < NPIX / 32; ++jt) {
        bf16x8 av = pa[jt * 4];
        bf16x8 b0 = pb0[jt * 4];
        bf16x8 b1 = pb1[jt * 4];
        acc0 = __builtin_amdgcn_mfma_f32_16x16x32_bf16(av, b0, acc0, 0, 0, 0);
        acc1 = __builtin_amdgcn_mfma_f32_16x16x32_bf16(av, b1, acc1, 0, 0, 0);
    }

    // epilogue: C/D layout col(label)=lane&15, row=kh*4+reg
    int n0 = m;
    int l1 = m + 16;
    #pragma unroll
    for (int r = 0; r < 4; ++r) {
        int i = i0 + kh * 4 + r;
        float nb = nbi[i];
        float lg0 = -U[n0 * NPIX + i] + SP[n0 * NPIX + i] + BI_W_C * nb * acc0[r];
        float lg1 = (l1 < LBL)
                  ? (-U[l1 * NPIX + i] + SP[l1 * NPIX + i] + BI_W_C * nb * acc1[r])
                  : -1e30f;
        float mx = fmaxf(lg0, lg1);
        #pragma unroll
        for (int off = 1; off < 16; off <<= 1) mx = fmaxf(mx, __shfl_xor(mx, off, 16));
        float e0 = __expf(lg0 - mx);
        float e1 = (l1 < LBL) ? __expf(lg1 - mx) : 0.f;
        float s = e0 + e1;
        #pragma unroll
        for (int off = 1; off < 16; off <<= 1) s += __shfl_xor(s, off, 16);
        float inv = 1.f / s;
        float q0 = e0 * inv;
        Qo[n0 * NPIX + i] = q0;
        Qto[n0 * NPIX + i] = f2bf(nb * q0);
        if (l1 < LBL) {
            float q1 = e1 * inv;
            Qo[l1 * NPIX + i] = q1;
            Qto[l1 * NPIX + i] = f2bf(nb * q1);
        }
    }
}

// ---------------------------------------------------------------- k_bi_slow
// fallback when ws too small for K: recompute K on the fly (VALU, fp32)
__global__ void k_bi_slow(const float* __restrict__ fx, const float* __restrict__ fy,
                          const float* __restrict__ fr, const float* __restrict__ fg,
                          const float* __restrict__ fb,
                          const float* __restrict__ nbi, const float* __restrict__ Q,
                          const float* __restrict__ U, const float* __restrict__ SP,
                          float* __restrict__ Qo, unsigned short* __restrict__ Qto) {
    int t = threadIdx.x;
    int px = t & 15, st = t >> 4;
    int i = blockIdx.x * 16 + px;
    float xi = fx[i], yi = fy[i], ri = fr[i], gi = fg[i], bi = fb[i];
    float acc[LBL];
    #pragma unroll
    for (int l = 0; l < LBL; ++l) acc[l] = 0.f;
    int j0 = st * (NPIX / 16);
    for (int j = j0; j < j0 + NPIX / 16; ++j) {
        float dx = xi - fx[j], dy = yi - fy[j];
        float dr = ri - fr[j], dg = gi - fg[j], db = bi - fb[j];
        float D = dx*dx + dy*dy + dr*dr + dg*dg + db*db;
        float w = __expf(-0.5f * D) * nbi[j];
        #pragma unroll
        for (int l = 0; l < LBL; ++l) acc[l] += w * Q[l * NPIX + j];
    }
    __shared__ float red[16][LBL];
    if (st == 0) {
        #pragma unroll
        for (int l = 0; l < LBL; ++l) red[px][l] = acc[l];
    }
    __syncthreads();
    for (int s = 1; s < 16; ++s) {
        if (st == s) {
            #pragma unroll
            for (int l = 0; l < LBL; ++l) red[px][l] += acc[l];
        }
        __syncthreads();
    }
    if (t < 16) {
        int i2 = blockIdx.x * 16 + t;
        float nb = nbi[i2];
        float v[LBL];
        float mx = -1e30f;
        #pragma unroll
        for (int l = 0; l < LBL; ++l) {
            v[l] = -U[l * NPIX + i2] + SP[l * NPIX + i2] + BI_W_C * nb * red[t][l];
            mx = fmaxf(mx, v[l]);
        }
        float s = 0.f;
        #pragma unroll
        for (int l = 0; l < LBL; ++l) { v[l] = __expf(v[l] - mx); s += v[l]; }
        float inv = 1.f / s;
        #pragma unroll
        for (int l = 0; l < LBL; ++l) {
            float q = v[l] * inv;
            Qo[l * NPIX + i2] = q;
            Qto[l * NPIX + i2] = f2bf(nb * q);
        }
    }
}

// ---------------------------------------------------------------- launch
extern "C" void kernel_launch(void* const* d_in, const int* in_sizes, int n_in,
                              void* d_out, int out_size, void* d_ws, size_t ws_size,
                              hipStream_t stream) {
    const float* U = (const float*)d_in[0];
    const float* I = (const float*)d_in[1];

    char* w = (char*)d_ws;
    float* fx  = (float*)w;                 w += NPIX * sizeof(float);
    float* fy  = (float*)w;                 w += NPIX * sizeof(float);
    float* fr  = (float*)w;                 w += NPIX * sizeof(float);
    float* fg  = (float*)w;                 w += NPIX * sizeof(float);
    float* fb  = (float*)w;                 w += NPIX * sizeof(float);
    float* nsp = (float*)w;                 w += NPIX * sizeof(float);
    float* nbi = (float*)w;                 w += NPIX * sizeof(float);
    float* SP  = (float*)w;                 w += (size_t)LBL * NPIX * sizeof(float);
    float* Qb[2];
    Qb[0] = (float*)w;                      w += (size_t)LBL * NPIX * sizeof(float);
    Qb[1] = (float*)w;                      w += (size_t)LBL * NPIX * sizeof(float);
    unsigned short* Qtb[2];
    Qtb[0] = (unsigned short*)w;            w += (size_t)LPAD * NPIX * sizeof(unsigned short);
    Qtb[1] = (unsigned short*)w;            w += (size_t)LPAD * NPIX * sizeof(unsigned short);
    unsigned short* K = (unsigned short*)w;
    size_t need = (size_t)(w - (char*)d_ws) + (size_t)NPIX * NPIX * sizeof(unsigned short);
    bool fast = (ws_size >= need);

    k_prep<<<(NPIX + 255) / 256, 256, 0, stream>>>(I, fx, fy, fr, fg, fb, nsp);
    if (fast) k_K<true ><<<NPIX, 256, 0, stream>>>(fx, fy, fr, fg, fb, nbi, K);
    else      k_K<false><<<NPIX, 256, 0, stream>>>(fx, fy, fr, fg, fb, nbi, nullptr);
    k_q0<<<(NPIX + 255) / 256, 256, 0, stream>>>(U, nbi, Qb[0], Qtb[0], Qtb[1]);

    for (int t = 0; t < N_ITER; ++t) {
        const float* Qin = Qb[t & 1];
        const unsigned short* Qtin = Qtb[t & 1];
        float* Qout = (t == N_ITER - 1) ? (float*)d_out : Qb[(t + 1) & 1];
        unsigned short* Qtout = Qtb[(t + 1) & 1];
        k_spatial<<<LBL, 256, 0, stream>>>(Qin, nsp, SP);
        if (fast)
            k_bi_fast<<<NPIX / 16, 64, 0, stream>>>(K, Qtin, U, SP, nbi, Qout, Qtout);
        else
            k_bi_slow<<<NPIX / 16, 256, 0, stream>>>(fx, fy, fr, fg, fb, nbi, Qin, U, SP, Qout, Qtout);
    }
}

// Round 2
// 1010.083 us; speedup vs baseline: 2.6734x; 2.6734x over previous
//
#include <hip/hip_runtime.h>
#include <stddef.h>

#define HH 96
#define WW 96
#define NPIX 9216
#define LBL 21
#define LPAD 32
#define RAD 9            // int(3 * POS_STD)
#define N_ITER 10
#define POS_W_C 3.0f
#define BI_W_C 10.0f
#define INV_XY (1.0f/80.0f)
#define INV_RGB (1.0f/13.0f)

typedef __bf16 bf16x8 __attribute__((ext_vector_type(8)));
typedef float  f32x4  __attribute__((ext_vector_type(4)));

// exp(-0.5*(d/3)^2), d = -9..9  (matches reference _gauss1d(3.0))
__device__ const float GK[2 * RAD + 1] = {
    0.01110900f, 0.02856548f, 0.06572886f, 0.13533528f, 0.24935220f,
    0.41111229f, 0.60653066f, 0.80073740f, 0.94595947f, 1.00000000f,
    0.94595947f, 0.80073740f, 0.60653066f, 0.41111229f, 0.24935220f,
    0.13533528f, 0.06572886f, 0.02856548f, 0.01110900f
};

__device__ __forceinline__ unsigned short f2bf(float f) {
    unsigned u = __float_as_uint(f);
    unsigned r = (u + 0x7fffu + ((u >> 16) & 1u)) >> 16;
    return (unsigned short)r;
}
__device__ __forceinline__ float bf2f(unsigned short s) {
    return __uint_as_float(((unsigned)s) << 16);
}

// ---------------------------------------------------------------- k_prep
// features (SoA), spatial normalizer nsp = rsqrt(Sy[y]*Sx[x])
__global__ void k_prep(const float* __restrict__ I,
                       float* __restrict__ fx, float* __restrict__ fy,
                       float* __restrict__ fr, float* __restrict__ fg,
                       float* __restrict__ fb, float* __restrict__ nsp) {
    int n = blockIdx.x * 256 + threadIdx.x;
    if (n >= NPIX) return;
    int y = n / WW, x = n % WW;
    fx[n] = (float)x * INV_XY;
    fy[n] = (float)y * INV_XY;
    fr[n] = I[n] * INV_RGB;
    fg[n] = I[NPIX + n] * INV_RGB;
    fb[n] = I[2 * NPIX + n] * INV_RGB;
    float sy = 0.f, sx = 0.f;
    #pragma unroll
    for (int d = -RAD; d <= RAD; ++d) {
        float g = GK[d + RAD];
        if ((unsigned)(y + d) < HH) sy += g;
        if ((unsigned)(x + d) < WW) sx += g;
    }
    nsp[n] = rsqrtf(sy * sx);
}

// ---------------------------------------------------------------- k_K
// one block per row i: K[i][j] (bf16, optional) + nbi[i] = rsqrt(sum_j K)
template <bool STORE>
__global__ void k_K(const float* __restrict__ fx, const float* __restrict__ fy,
                    const float* __restrict__ fr, const float* __restrict__ fg,
                    const float* __restrict__ fb,
                    float* __restrict__ nbi, unsigned short* __restrict__ K) {
    int i = blockIdx.x;
    int t = threadIdx.x;
    float xi = fx[i], yi = fy[i], ri = fr[i], gi = fg[i], bi = fb[i];
    float sum = 0.f;
    for (int jt = t; jt < NPIX / 4; jt += 256) {
        int j = jt * 4;
        float4 vx = *(const float4*)(fx + j);
        float4 vy = *(const float4*)(fy + j);
        float4 vr = *(const float4*)(fr + j);
        float4 vg = *(const float4*)(fg + j);
        float4 vb = *(const float4*)(fb + j);
        float k0, k1, k2, k3;
        {
            float dx = xi - vx.x, dy = yi - vy.x, dr = ri - vr.x, dg = gi - vg.x, db = bi - vb.x;
            k0 = __expf(-0.5f * (dx*dx + dy*dy + dr*dr + dg*dg + db*db));
        }
        {
            float dx = xi - vx.y, dy = yi - vy.y, dr = ri - vr.y, dg = gi - vg.y, db = bi - vb.y;
            k1 = __expf(-0.5f * (dx*dx + dy*dy + dr*dr + dg*dg + db*db));
        }
        {
            float dx = xi - vx.z, dy = yi - vy.z, dr = ri - vr.z, dg = gi - vg.z, db = bi - vb.z;
            k2 = __expf(-0.5f * (dx*dx + dy*dy + dr*dr + dg*dg + db*db));
        }
        {
            float dx = xi - vx.w, dy = yi - vy.w, dr = ri - vr.w, dg = gi - vg.w, db = bi - vb.w;
            k3 = __expf(-0.5f * (dx*dx + dy*dy + dr*dr + dg*dg + db*db));
        }
        sum += (k0 + k1) + (k2 + k3);
        if (STORE) {
            ushort4 s;
            s.x = f2bf(k0); s.y = f2bf(k1); s.z = f2bf(k2); s.w = f2bf(k3);
            *(ushort4*)(K + (size_t)i * NPIX + j) = s;
        }
    }
    __shared__ float red[256];
    red[t] = sum;
    __syncthreads();
    #pragma unroll
    for (int s = 128; s > 0; s >>= 1) {
        if (t < s) red[t] += red[t + s];
        __syncthreads();
    }
    if (t == 0) nbi[i] = rsqrtf(red[0]);
}

// ---------------------------------------------------------------- k_q0
// Q0 = softmax(-U); A = nsp*Q0 (f32); Qt0 = bf16(nbi*Q0); zero pad rows of both Qt
__global__ void k_q0(const float* __restrict__ U, const float* __restrict__ nbi,
                     const float* __restrict__ nsp, float* __restrict__ A,
                     unsigned short* __restrict__ Qt0, unsigned short* __restrict__ Qt1) {
    int n = blockIdx.x * 256 + threadIdx.x;
    if (n >= NPIX) return;
    float v[LBL];
    float mx = -1e30f;
    #pragma unroll
    for (int l = 0; l < LBL; ++l) { v[l] = -U[l * NPIX + n]; mx = fmaxf(mx, v[l]); }
    float s = 0.f;
    #pragma unroll
    for (int l = 0; l < LBL; ++l) { v[l] = __expf(v[l] - mx); s += v[l]; }
    float inv = 1.f / s;
    float nb = nbi[n];
    float ns = nsp[n];
    #pragma unroll
    for (int l = 0; l < LBL; ++l) {
        float q = v[l] * inv;
        A[l * NPIX + n] = ns * q;
        Qt0[l * NPIX + n] = f2bf(nb * q);
    }
    #pragma unroll
    for (int l = LBL; l < LPAD; ++l) { Qt0[l * NPIX + n] = 0; Qt1[l * NPIX + n] = 0; }
}

// ---------------------------------------------------------------- k_sp_v
// tmp = conv_y(A), grid-parallel over all LBL*NPIX elements
__global__ void k_sp_v(const float* __restrict__ A, float* __restrict__ tmp) {
    int n = blockIdx.x * 256 + threadIdx.x;   // LBL*NPIX == 756*256 exactly
    int p = n % NPIX;
    int y = p / WW;
    float s = 0.f;
    #pragma unroll
    for (int d = -RAD; d <= RAD; ++d) {
        if ((unsigned)(y + d) < HH) s += GK[d + RAD] * A[n + d * WW];
    }
    tmp[n] = s;
}

// ---------------------------------------------------------------- k_sp_h
// SP = POS_W * nsp * conv_x(tmp)
__global__ void k_sp_h(const float* __restrict__ tmp, const float* __restrict__ nsp,
                       float* __restrict__ SP) {
    int n = blockIdx.x * 256 + threadIdx.x;
    int p = n % NPIX;
    int x = p % WW;
    float s = 0.f;
    #pragma unroll
    for (int d = -RAD; d <= RAD; ++d) {
        if ((unsigned)(x + d) < WW) s += GK[d + RAD] * tmp[n + d];
    }
    SP[n] = POS_W_C * nsp[p] * s;
}

// ---------------------------------------------------------------- k_bi_fast
// 4 waves per 16 pixels, each wave 1/4 of j; LDS reduce; fused softmax epilogue
__global__ void __launch_bounds__(256)
k_bi_fast(const unsigned short* __restrict__ K, const unsigned short* __restrict__ Qt,
          const float* __restrict__ U, const float* __restrict__ SP,
          const float* __restrict__ nbi, const float* __restrict__ nsp,
          float* __restrict__ Qo, float* __restrict__ Ao,
          unsigned short* __restrict__ Qto) {
    int tid = threadIdx.x;
    int lane = tid & 63;
    int wv = tid >> 6;      // 0..3, j-split
    int m  = lane & 15;     // A row / B col / label index
    int kh = lane >> 4;     // k-quad
    int i0 = blockIdx.x * 16;

    const int JW = NPIX / 4;        // j elements per wave
    int jbase = wv * JW;

    const bf16x8* pa  = (const bf16x8*)(K  + (size_t)(i0 + m) * NPIX + jbase + kh * 8);
    const bf16x8* pb0 = (const bf16x8*)(Qt + (size_t)m        * NPIX + jbase + kh * 8);
    const bf16x8* pb1 = (const bf16x8*)(Qt + (size_t)(m + 16) * NPIX + jbase + kh * 8);

    f32x4 acc0 = {0.f, 0.f, 0.f, 0.f};
    f32x4 acc1 = {0.f, 0.f, 0.f, 0.f};

    #pragma unroll 4
    for (int jt = 0; jt < JW / 32; ++jt) {   // 72 iters
        bf16x8 av = pa[jt * 4];
        bf16x8 b0 = pb0[jt * 4];
        bf16x8 b1 = pb1[jt * 4];
        acc0 = __builtin_amdgcn_mfma_f32_16x16x32_bf16(av, b0, acc0, 0, 0, 0);
        acc1 = __builtin_amdgcn_mfma_f32_16x16x32_bf16(av, b1, acc1, 0, 0, 0);
    }

    __shared__ float red[4][8][64];   // [wave][reg][lane] — conflict-free
    #pragma unroll
    for (int r = 0; r < 4; ++r) {
        red[wv][r][lane]     = acc0[r];
        red[wv][r + 4][lane] = acc1[r];
    }
    __syncthreads();
    if (wv != 0) return;

    #pragma unroll
    for (int r = 0; r < 4; ++r) {
        acc0[r] += red[1][r][lane] + red[2][r][lane] + red[3][r][lane];
        acc1[r] += red[1][r + 4][lane] + red[2][r + 4][lane] + red[3][r + 4][lane];
    }

    // epilogue: C/D layout col(label)=lane&15, row=kh*4+reg
    int n0 = m;
    int l1 = m + 16;
    #pragma unroll
    for (int r = 0; r < 4; ++r) {
        int i = i0 + kh * 4 + r;
        float nb = nbi[i];
        float lg0 = -U[n0 * NPIX + i] + SP[n0 * NPIX + i] + BI_W_C * nb * acc0[r];
        float lg1 = (l1 < LBL)
                  ? (-U[l1 * NPIX + i] + SP[l1 * NPIX + i] + BI_W_C * nb * acc1[r])
                  : -1e30f;
        float mx = fmaxf(lg0, lg1);
        #pragma unroll
        for (int off = 1; off < 16; off <<= 1) mx = fmaxf(mx, __shfl_xor(mx, off, 16));
        float e0 = __expf(lg0 - mx);
        float e1 = (l1 < LBL) ? __expf(lg1 - mx) : 0.f;
        float s = e0 + e1;
        #pragma unroll
        for (int off = 1; off < 16; off <<= 1) s += __shfl_xor(s, off, 16);
        float inv = 1.f / s;
        float ns = nsp[i];
        float q0 = e0 * inv;
        Qo[n0 * NPIX + i] = q0;
        Ao[n0 * NPIX + i] = ns * q0;
        Qto[n0 * NPIX + i] = f2bf(nb * q0);
        if (l1 < LBL) {
            float q1 = e1 * inv;
            Qo[l1 * NPIX + i] = q1;
            Ao[l1 * NPIX + i] = ns * q1;
            Qto[l1 * NPIX + i] = f2bf(nb * q1);
        }
    }
}

// ---------------------------------------------------------------- k_bi_slow
// fallback when ws too small for K: recompute K on the fly (VALU, fp32)
__global__ void k_bi_slow(const float* __restrict__ fx, const float* __restrict__ fy,
                          const float* __restrict__ fr, const float* __restrict__ fg,
                          const float* __restrict__ fb,
                          const float* __restrict__ nbi, const unsigned short* __restrict__ Qt,
                          const float* __restrict__ U, const float* __restrict__ SP,
                          const float* __restrict__ nsp,
                          float* __restrict__ Qo, float* __restrict__ Ao,
                          unsigned short* __restrict__ Qto) {
    int t = threadIdx.x;
    int px = t & 15, st = t >> 4;
    int i = blockIdx.x * 16 + px;
    float xi = fx[i], yi = fy[i], ri = fr[i], gi = fg[i], bi = fb[i];
    float acc[LBL];
    #pragma unroll
    for (int l = 0; l < LBL; ++l) acc[l] = 0.f;
    int j0 = st * (NPIX / 16);
    for (int j = j0; j < j0 + NPIX / 16; ++j) {
        float dx = xi - fx[j], dy = yi - fy[j];
        float dr = ri - fr[j], dg = gi - fg[j], db = bi - fb[j];
        float D = dx*dx + dy*dy + dr*dr + dg*dg + db*db;
        float w = __expf(-0.5f * D);
        #pragma unroll
        for (int l = 0; l < LBL; ++l) acc[l] += w * bf2f(Qt[l * NPIX + j]);
    }
    __shared__ float red[16][LBL];
    if (st == 0) {
        #pragma unroll
        for (int l = 0; l < LBL; ++l) red[px][l] = acc[l];
    }
    __syncthreads();
    for (int s = 1; s < 16; ++s) {
        if (st == s) {
            #pragma unroll
            for (int l = 0; l < LBL; ++l) red[px][l] += acc[l];
        }
        __syncthreads();
    }
    if (t < 16) {
        int i2 = blockIdx.x * 16 + t;
        float nb = nbi[i2];
        float ns = nsp[i2];
        float v[LBL];
        float mx = -1e30f;
        #pragma unroll
        for (int l = 0; l < LBL; ++l) {
            v[l] = -U[l * NPIX + i2] + SP[l * NPIX + i2] + BI_W_C * nb * red[t][l];
            mx = fmaxf(mx, v[l]);
        }
        float s = 0.f;
        #pragma unroll
        for (int l = 0; l < LBL; ++l) { v[l] = __expf(v[l] - mx); s += v[l]; }
        float inv = 1.f / s;
        #pragma unroll
        for (int l = 0; l < LBL; ++l) {
            float q = v[l] * inv;
            Qo[l * NPIX + i2] = q;
            Ao[l * NPIX + i2] = ns * q;
            Qto[l * NPIX + i2] = f2bf(nb * q);
        }
    }
}

// ---------------------------------------------------------------- launch
extern "C" void kernel_launch(void* const* d_in, const int* in_sizes, int n_in,
                              void* d_out, int out_size, void* d_ws, size_t ws_size,
                              hipStream_t stream) {
    const float* U = (const float*)d_in[0];
    const float* I = (const float*)d_in[1];

    char* w = (char*)d_ws;
    float* fx  = (float*)w;                 w += NPIX * sizeof(float);
    float* fy  = (float*)w;                 w += NPIX * sizeof(float);
    float* fr  = (float*)w;                 w += NPIX * sizeof(float);
    float* fg  = (float*)w;                 w += NPIX * sizeof(float);
    float* fb  = (float*)w;                 w += NPIX * sizeof(float);
    float* nsp = (float*)w;                 w += NPIX * sizeof(float);
    float* nbi = (float*)w;                 w += NPIX * sizeof(float);
    float* A   = (float*)w;                 w += (size_t)LBL * NPIX * sizeof(float);
    float* tmp = (float*)w;                 w += (size_t)LBL * NPIX * sizeof(float);
    float* SP  = (float*)w;                 w += (size_t)LBL * NPIX * sizeof(float);
    unsigned short* Qtb[2];
    Qtb[0] = (unsigned short*)w;            w += (size_t)LPAD * NPIX * sizeof(unsigned short);
    Qtb[1] = (unsigned short*)w;            w += (size_t)LPAD * NPIX * sizeof(unsigned short);
    unsigned short* K = (unsigned short*)w;
    size_t need = (size_t)(w - (char*)d_ws) + (size_t)NPIX * NPIX * sizeof(unsigned short);
    bool fast = (ws_size >= need);

    float* Qout = (float*)d_out;   // overwritten every iteration; final iter is the answer

    k_prep<<<(NPIX + 255) / 256, 256, 0, stream>>>(I, fx, fy, fr, fg, fb, nsp);
    if (fast) k_K<true ><<<NPIX, 256, 0, stream>>>(fx, fy, fr, fg, fb, nbi, K);
    else      k_K<false><<<NPIX, 256, 0, stream>>>(fx, fy, fr, fg, fb, nbi, nullptr);
    k_q0<<<(NPIX + 255) / 256, 256, 0, stream>>>(U, nbi, nsp, A, Qtb[0], Qtb[1]);

    for (int t = 0; t < N_ITER; ++t) {
        const unsigned short* Qtin = Qtb[t & 1];
        unsigned short* Qtout = Qtb[(t + 1) & 1];
        k_sp_v<<<LBL * NPIX / 256, 256, 0, stream>>>(A, tmp);
        k_sp_h<<<LBL * NPIX / 256, 256, 0, stream>>>(tmp, nsp, SP);
        if (fast)
            k_bi_fast<<<NPIX / 16, 256, 0, stream>>>(K, Qtin, U, SP, nbi, nsp, Qout, A, Qtout);
        else
            k_bi_slow<<<NPIX / 16, 256, 0, stream>>>(fx, fy, fr, fg, fb, nbi, Qtin, U, SP, nsp, Qout, A, Qtout);
    }
}